// Round 4
// baseline (2417.638 us; speedup 1.0000x reference)
//
#include <hip/hip_runtime.h>

typedef unsigned short u16;
typedef unsigned int   u32;
typedef unsigned long long u64;
typedef short s16x8 __attribute__((ext_vector_type(8)));
typedef float f32x4 __attribute__((ext_vector_type(4)));

#define S_LEN 2048
#define BATCH 64
#define H_DIM 300
#define HP    304   // padded N (output) dim
#define KP    320   // padded K (contraction) dim

// ws layout (bytes)
#define OFF_WPAD 0u         // 304*320*2 = 194,560
#define OFF_BIAS 196608u    // 304*4
#define OFF_FLAG 198656u    // 4
#define OFF_H    200704u    // 64*304*4 = 77,824
#define OFF_POOL 278528u    // 2048*304*4 = 2,490,368
#define OFF_XP   2768896u   // CH*64*304*4 (f32)

__device__ __forceinline__ float bf2f(u16 u){
  union { u32 i; float f; } v; v.i = ((u32)u) << 16; return v.f;
}
__device__ __forceinline__ u16 f2bf(float f){
  u32 i = __float_as_uint(f);
  u32 r = (i + 0x7fffu + ((i >> 16) & 1u)) >> 16;
  return (u16)r;
}

// ---------------------------------------------------------------------------
// detect: f32 vs bf16 input storage. bf16 emb ~N(0,0.02^2) has exponent
// field < 135 always; f32 words read as u16 have ~uniform low-mantissa bits.
// ---------------------------------------------------------------------------
__global__ __launch_bounds__(256) void detect(const u16* __restrict__ emb_raw,
                                              int* __restrict__ flag){
  __shared__ int big;
  if (threadIdx.x == 0) big = 0;
  __syncthreads();
  int loc = 0;
  for (int i = threadIdx.x; i < 1024; i += 256){
    const u32 e = ((u32)emb_raw[i] >> 7) & 0xFFu;
    if (e >= 135u) loc = 1;
  }
  if (loc) atomicOr(&big, 1);
  __syncthreads();
  if (threadIdx.x == 0) *flag = big;   // 1 = f32 inputs, 0 = bf16 inputs
}

// ---------------------------------------------------------------------------
// prep: zero pooled[2048][304], hstate[64][304]; build zero-padded bf16
// W_ih [304][320]; fused fp32 bias b_ih+b_hh [304].
// ---------------------------------------------------------------------------
__global__ __launch_bounds__(256) void prep(
    const void* __restrict__ Wih_raw, const void* __restrict__ bih_raw,
    const void* __restrict__ bhh_raw, const int* __restrict__ flag,
    u16* __restrict__ Wpad, float* __restrict__ biasp,
    float* __restrict__ pooled, float* __restrict__ hstate)
{
  const bool isf32 = (*flag != 0);
  const int idx = blockIdx.x * 256 + threadIdx.x;
  if (idx < S_LEN * HP) pooled[idx] = 0.f;
  if (idx < BATCH * HP) hstate[idx] = 0.f;
  if (idx < HP * KP){
    const int n = idx / KP, k = idx % KP;
    u16 v = 0;
    if (n < H_DIM && k < H_DIM){
      v = isf32 ? f2bf(((const float*)Wih_raw)[n * H_DIM + k])
                : ((const u16*)Wih_raw)[n * H_DIM + k];
    }
    Wpad[idx] = v;
  }
  if (idx < HP){
    float bv = 0.f;
    if (idx < H_DIM){
      bv = isf32 ? (((const float*)bih_raw)[idx] + ((const float*)bhh_raw)[idx])
                 : (bf2f(((const u16*)bih_raw)[idx]) + bf2f(((const u16*)bhh_raw)[idx]));
    }
    biasp[idx] = bv;
  }
}

// ---------------------------------------------------------------------------
// xp_gemm: xp[mrel][n] = emb[x[s0*64+mrel]] . W_ih[n,:] + b_ih[n] + b_hh[n]
// One block = 64 m-rows, 4 waves, MFMA 16x16x32 bf16. xp stored f32.
// ---------------------------------------------------------------------------
__global__ __launch_bounds__(256) void xp_gemm(
    const int* __restrict__ x, const void* __restrict__ emb_raw,
    const int* __restrict__ flag,
    const u16* __restrict__ Wpad, const float* __restrict__ biasp,
    float* __restrict__ xp, int s0)
{
  __shared__ u16 A[64 * KP];                 // 40 KB
  const bool isf32 = (*flag != 0);
  const int tid = threadIdx.x;
  const int m0g = s0 * BATCH + blockIdx.x * 64;   // global m of row 0
  const int m0r = blockIdx.x * 64;                // chunk-relative

  // zero the k-pad tail (k 300..319) of each row
  for (int t = tid; t < 640; t += 256){
    const int row = t / 10, wd = t % 10;
    *(u32*)&A[row * KP + H_DIM + wd * 2] = 0u;
  }
  // gather 64 embedding rows, 4 elements per thread-iteration
  for (int t = tid; t < 64 * 75; t += 256){
    const int row = t / 75, off = t % 75;
    const int tok = x[m0g + row];
    u64 pk;
    if (isf32){
      const float4 v = *(const float4*)((const float*)emb_raw + (size_t)tok * H_DIM + off * 4);
      pk = (u64)f2bf(v.x) | ((u64)f2bf(v.y) << 16)
         | ((u64)f2bf(v.z) << 32) | ((u64)f2bf(v.w) << 48);
    } else {
      pk = *(const u64*)((const u16*)emb_raw + (size_t)tok * H_DIM + off * 4);
    }
    *(u64*)&A[row * KP + off * 4] = pk;
  }
  __syncthreads();

  const int wave = tid >> 6, lane = tid & 63;
  const int lm = lane & 15, lq = lane >> 4;

  f32x4 acc[19];
#pragma unroll
  for (int nt = 0; nt < 19; ++nt) acc[nt] = (f32x4){0.f, 0.f, 0.f, 0.f};

#pragma unroll
  for (int ks = 0; ks < 10; ++ks){
    const int k = ks * 32 + lq * 8;
    const s16x8 af = *(const s16x8*)&A[(wave * 16 + lm) * KP + k];
#pragma unroll
    for (int nt = 0; nt < 19; ++nt){
      const s16x8 bf = *(const s16x8*)&Wpad[(nt * 16 + lm) * KP + k];
      acc[nt] = __builtin_amdgcn_mfma_f32_16x16x32_bf16(af, bf, acc[nt], 0, 0, 0);
    }
  }
  // C/D layout: col = lane&15 (from B), row = (lane>>4)*4 + reg (verified)
#pragma unroll
  for (int nt = 0; nt < 19; ++nt){
    const int n = nt * 16 + lm;
    const float bv = biasp[n];
#pragma unroll
    for (int rr = 0; rr < 4; ++rr){
      const int m = m0r + wave * 16 + lq * 4 + rr;
      xp[(size_t)m * HP + n] = acc[nt][rr] + bv;
    }
  }
}

// ---------------------------------------------------------------------------
// recur: one block per batch element b, len steps starting at global s0.
// 512 threads = 8 waves. Thread (c=tid>>6, rg=tid&63) owns rows rg*5..+4,
// j-chunk [c*40,c*40+40) of W_hh in 200 fp32 VGPRs. h in LDS fp32,
// wave-uniform float4 broadcasts; 8 partials/row reduced via LDS.
// ---------------------------------------------------------------------------
__global__ __launch_bounds__(512, 2) void recur(
    const float* __restrict__ xp, const void* __restrict__ Whh_raw,
    const int* __restrict__ flag,
    float* __restrict__ hstate, float* __restrict__ pooled,
    float* __restrict__ dout, int s0, int len)
{
  const bool isf32 = (*flag != 0);
  const int b   = blockIdx.x;
  const int tid = threadIdx.x;
  const int c   = tid >> 6;
  const int rg  = tid & 63;

  __shared__ float h_f[KP];        // 320 floats, pads stay 0
  __shared__ float part[40][64];   // [c*5+r][rg]

  float w[5][40];
#pragma unroll
  for (int r = 0; r < 5; ++r){
    const int row = rg * 5 + r;
#pragma unroll
    for (int p = 0; p < 40; ++p){
      const int k = c * 40 + p;
      float wv = 0.f;
      if (row < H_DIM && k < H_DIM){
        wv = isf32 ? ((const float*)Whh_raw)[row * H_DIM + k]
                   : bf2f(((const u16*)Whh_raw)[row * H_DIM + k]);
      }
      w[r][p] = wv;
    }
  }
  if (tid < KP) h_f[tid] = (tid < HP) ? hstate[b * HP + tid] : 0.f;

  const int r5 = tid % 5, rg5 = tid / 5;
  const float* xpb = xp + (size_t)b * HP;        // chunk row t -> t*64+b
  float xv = (tid < HP) ? xpb[tid] : 0.f;        // t = 0
  __syncthreads();

  for (int t = 0; t < len; ++t){
    const float xpv = xv;
    const int tn = (t + 1 < len) ? (t + 1) : t;
    const float xnext = (tid < HP) ? xpb[(size_t)tn * (BATCH * HP) + tid] : 0.f;

    float a0 = 0.f, a1 = 0.f, a2 = 0.f, a3 = 0.f, a4 = 0.f;
#pragma unroll
    for (int q = 0; q < 10; ++q){
      const float4 hv = *(const float4*)&h_f[c * 40 + q * 4];
      a0 = fmaf(w[0][4*q+0], hv.x, a0); a0 = fmaf(w[0][4*q+1], hv.y, a0);
      a0 = fmaf(w[0][4*q+2], hv.z, a0); a0 = fmaf(w[0][4*q+3], hv.w, a0);
      a1 = fmaf(w[1][4*q+0], hv.x, a1); a1 = fmaf(w[1][4*q+1], hv.y, a1);
      a1 = fmaf(w[1][4*q+2], hv.z, a1); a1 = fmaf(w[1][4*q+3], hv.w, a1);
      a2 = fmaf(w[2][4*q+0], hv.x, a2); a2 = fmaf(w[2][4*q+1], hv.y, a2);
      a2 = fmaf(w[2][4*q+2], hv.z, a2); a2 = fmaf(w[2][4*q+3], hv.w, a2);
      a3 = fmaf(w[3][4*q+0], hv.x, a3); a3 = fmaf(w[3][4*q+1], hv.y, a3);
      a3 = fmaf(w[3][4*q+2], hv.z, a3); a3 = fmaf(w[3][4*q+3], hv.w, a3);
      a4 = fmaf(w[4][4*q+0], hv.x, a4); a4 = fmaf(w[4][4*q+1], hv.y, a4);
      a4 = fmaf(w[4][4*q+2], hv.z, a4); a4 = fmaf(w[4][4*q+3], hv.w, a4);
    }
    part[c*5+0][rg] = a0;
    part[c*5+1][rg] = a1;
    part[c*5+2][rg] = a2;
    part[c*5+3][rg] = a3;
    part[c*5+4][rg] = a4;
    __syncthreads();

    if (tid < H_DIM){
      float sum = 0.f;
#pragma unroll
      for (int cc = 0; cc < 8; ++cc) sum += part[cc*5 + r5][rg5];
      float h = sum + xpv;
      h = fmaxf(h, 0.f);
      const int s = s0 + t;
      atomicMax((u32*)(pooled + (size_t)s * HP + tid), __float_as_uint(h));
      h_f[tid] = h;
      if (s == S_LEN - 1) dout[S_LEN * 2 + b * H_DIM + tid] = h;  // f32 hidden
    }
    xv = xnext;
    __syncthreads();
  }
  if (tid < HP) hstate[b * HP + tid] = h_f[tid];
}

// ---------------------------------------------------------------------------
// outproj: out[s][c] = sum_i pooled[s][i] * W_out[c][i] + b_out[c]  (f32 out)
// ---------------------------------------------------------------------------
__global__ __launch_bounds__(128) void outproj(
    const float* __restrict__ pooled, const void* __restrict__ Wout_raw,
    const void* __restrict__ bout_raw, const int* __restrict__ flag,
    float* __restrict__ dout)
{
  const bool isf32 = (*flag != 0);
  const int s = blockIdx.x * 128 + threadIdx.x;   // 0..2047
  float a0, a1;
  if (isf32){ a0 = ((const float*)bout_raw)[0]; a1 = ((const float*)bout_raw)[1]; }
  else      { a0 = bf2f(((const u16*)bout_raw)[0]); a1 = bf2f(((const u16*)bout_raw)[1]); }
  for (int i = 0; i < H_DIM; ++i){
    const float p = pooled[(size_t)s * HP + i];
    float w0, w1;
    if (isf32){ w0 = ((const float*)Wout_raw)[i]; w1 = ((const float*)Wout_raw)[H_DIM + i]; }
    else      { w0 = bf2f(((const u16*)Wout_raw)[i]); w1 = bf2f(((const u16*)Wout_raw)[H_DIM + i]); }
    a0 = fmaf(p, w0, a0);
    a1 = fmaf(p, w1, a1);
  }
  dout[s * 2 + 0] = a0;
  dout[s * 2 + 1] = a1;
}

// ---------------------------------------------------------------------------
extern "C" void kernel_launch(void* const* d_in, const int* in_sizes, int n_in,
                              void* d_out, int out_size, void* d_ws, size_t ws_size,
                              hipStream_t stream)
{
  const int* x  = (const int*)d_in[0];
  const void* emb  = d_in[1];
  const void* Wih  = d_in[2];
  const void* Whh  = d_in[3];
  const void* bih  = d_in[4];
  const void* bhh  = d_in[5];
  const void* Wout = d_in[6];
  const void* bout = d_in[7];
  float* out = (float*)d_out;

  char* ws = (char*)d_ws;
  u16*   Wpad   = (u16*)(ws + OFF_WPAD);
  float* biasp  = (float*)(ws + OFF_BIAS);
  int*   flag   = (int*)(ws + OFF_FLAG);
  float* hstate = (float*)(ws + OFF_H);
  float* pooled = (float*)(ws + OFF_POOL);
  float* xp     = (float*)(ws + OFF_XP);

  // choose chunk size (steps) so OFF_XP + CH*64*304*4 fits in ws_size
  const size_t per_step = (size_t)BATCH * HP * 4;   // 77,824 B
  int CH = 16;
  const int cands[8] = {2048, 1024, 512, 256, 128, 64, 32, 16};
  for (int i = 0; i < 8; ++i){
    if ((size_t)OFF_XP + (size_t)cands[i] * per_step <= ws_size){ CH = cands[i]; break; }
  }
  const int nchunks = S_LEN / CH;

  detect<<<1, 256, 0, stream>>>((const u16*)emb, flag);
  prep<<<2432, 256, 0, stream>>>(Wih, bih, bhh, flag, Wpad, biasp, pooled, hstate);
  for (int k = 0; k < nchunks; ++k){
    const int s0 = k * CH;
    xp_gemm<<<CH, 256, 0, stream>>>(x, emb, flag, Wpad, biasp, xp, s0);
    recur<<<64, 512, 0, stream>>>(xp, Whh, flag, hstate, pooled, out, s0, CH);
  }
  outproj<<<16, 128, 0, stream>>>(pooled, Wout, bout, flag, out);
}